// Round 11
// baseline (157.972 us; speedup 1.0000x reference)
//
#include <hip/hip_runtime.h>
#include <hip/hip_bf16.h>

#define B_ 4
#define H_ 16
#define N_ 2048
#define D_ 64
#define BM 128   // q-rows per WG (32 per wave, 4 waves)

typedef __bf16 bf16;
typedef bf16 bf16x4 __attribute__((ext_vector_type(4)));
typedef bf16 bf16x8 __attribute__((ext_vector_type(8)));
typedef float f32x16 __attribute__((ext_vector_type(16)));
typedef unsigned u32x2 __attribute__((ext_vector_type(2)));
typedef unsigned u32x4 __attribute__((ext_vector_type(4)));

#define SCALE_LOG2E 0.18033688011112042f  // (1/sqrt(64)) * log2(e)

#define GBL(p) ((const __attribute__((address_space(1))) void*)(p))
#define LDS(p) ((__attribute__((address_space(3))) void*)(p))

// Per (b, kv-tile T of 64): 16 KB image in per-lane FRAGMENT ORDER for 32x32x16 MFMA.
//   K half  [0,8KB):  unit p=(mt*4+ks)*64+ln : A-frag K[kv=T*64+mt*32+(ln&31)][d=ks*16+(ln>>5)*8 ..+8]
//   V half  [8,16KB): unit p=(mt*4+ks)*64+ln : A-frag V^T[d=mt*32+(ln&31)][kv=T*64+ks*16+(ln>>5)*8 ..+8]
// V transpose via LDS: coalesced float4 row reads -> padded LDS -> fragment-order
// reads -> coalesced bf16x8 store. One block per tile.
__global__ __launch_bounds__(512) void convert_kv(const float* __restrict__ k,
                                                  const float* __restrict__ v,
                                                  bf16* __restrict__ img) {
    __shared__ bf16 VT[64][66];                   // stride 66 elems (132 B)
    const int tile = blockIdx.x;                  // b*32 + T
    const int b = tile >> 5, T = tile & 31;
    const int t = threadIdx.x;                    // 0..511 == unit id
    bf16* timg = img + (size_t)tile * 8192;       // 16 KB per tile

    const int mtks = t >> 6;
    const int ln   = t & 63;
    const int mt = mtks >> 2, ks = mtks & 3;

    // --- K half: direct, coalesced both sides ---
    {
        const int kvr = T * 64 + mt * 32 + (ln & 31);
        const int d0  = ks * 16 + (ln >> 5) * 8;
        const float* src = k + ((size_t)b * N_ + kvr) * D_ + d0;
        float4 a = *(const float4*)src;
        float4 c = *(const float4*)(src + 4);
        bf16x8 o;
        o[0] = (bf16)a.x; o[1] = (bf16)a.y; o[2] = (bf16)a.z; o[3] = (bf16)a.w;
        o[4] = (bf16)c.x; o[5] = (bf16)c.y; o[6] = (bf16)c.z; o[7] = (bf16)c.w;
        *(bf16x8*)(timg + t * 8) = o;
    }

    // --- V half phase 1: coalesced row load -> LDS bf16 ---
    {
        const int kv = t >> 3;                    // 0..63 (tile-local row)
        const int c8 = (t & 7) * 8;               // 0..56
        const float* src = v + ((size_t)b * N_ + T * 64 + kv) * D_ + c8;
        float4 a = *(const float4*)src;
        float4 c = *(const float4*)(src + 4);
        VT[kv][c8 + 0] = (bf16)a.x; VT[kv][c8 + 1] = (bf16)a.y;
        VT[kv][c8 + 2] = (bf16)a.z; VT[kv][c8 + 3] = (bf16)a.w;
        VT[kv][c8 + 4] = (bf16)c.x; VT[kv][c8 + 5] = (bf16)c.y;
        VT[kv][c8 + 6] = (bf16)c.z; VT[kv][c8 + 7] = (bf16)c.w;
    }
    __syncthreads();
    // --- V half phase 2: fragment-order read, coalesced store ---
    {
        const int d   = mt * 32 + (ln & 31);
        const int kv0 = ks * 16 + (ln >> 5) * 8;  // tile-local
        bf16x8 o;
        #pragma unroll
        for (int j = 0; j < 8; ++j) o[j] = VT[kv0 + j][d];
        *(bf16x8*)(timg + 4096 + t * 8) = o;
    }
}

static __device__ inline bf16x4 pack4(float a, float b, float c, float d) {
    bf16x4 r; r[0] = (bf16)a; r[1] = (bf16)b; r[2] = (bf16)c; r[3] = (bf16)d; return r;
}

// C->B half-wave exchange via v_permlane32_swap_b32. For (p,q) = swap(L,H):
//   p = {L.row0, H.row0}  == (half ? xhi : lo)
//   q = {L.row1, H.row1}  == (half ? hi  : xlo)
static __device__ inline bf16x8 cswap(bf16x4 lo, bf16x4 hi) {
    u32x2 l = __builtin_bit_cast(u32x2, lo);
    u32x2 h = __builtin_bit_cast(u32x2, hi);
    u32x2 r0 = __builtin_amdgcn_permlane32_swap(l[0], h[0], false, false);
    u32x2 r1 = __builtin_amdgcn_permlane32_swap(l[1], h[1], false, false);
    u32x4 o; o[0] = r0[0]; o[1] = r1[0]; o[2] = r0[1]; o[3] = r1[1];
    return __builtin_bit_cast(bf16x8, o);
}

// Flash attention, 32x32x16 MFMA, S^T/O^T orientation, P in registers.
//
// Round-11 = R8 (best, 80.2us) + DENOMINATOR ON THE MFMA PIPE.
// R10 lesson: any register growth that drops occupancy loses; R8's exact
// structure is the budget ceiling. R8's tallest pipe is VALU (44.6%).
// The ones-row MFMA (R7: proven FREE on the MFMA pipe, +33% FLOPs at
// +-0us) moves the 32 adds/tile + lacc + epilogue shfl off the VALU;
// at R7's barrier-locked structure the saving was masked by serial-chain
// stalls -- R8's pipeline removed those, so the VALU saving should now
// convert to time. accL chain is off the critical path (read only in
// the epilogue). Net regs: +16 (accL) -1 (lacc).
__global__ __launch_bounds__(256, 2) void attn_fwd(const float* __restrict__ q,
                                                   const bf16* __restrict__ img,
                                                   float* __restrict__ out) {
    __shared__ __align__(16) bf16 KV3[3][8192];   // 3-slot ring, 48 KB

    const int tid  = threadIdx.x;
    const int lane = tid & 63;
    const int wv   = tid >> 6;          // 0..3
    const int half = lane >> 5;
    const int l31  = lane & 31;

    const int bh = blockIdx.y;
    const int b  = bh >> 4;
    const int q0 = blockIdx.x * BM + wv * 32;

    const bf16* tiles = img + (size_t)b * 32 * 8192;

    // Q frags (B-layout for S^T: n=q=l31, k=d=ks*16+half*8+j), pre-scaled
    bf16x8 qf[4];
    #pragma unroll
    for (int ks = 0; ks < 4; ++ks) {
        const float* src = q + ((size_t)bh * N_ + q0 + l31) * D_ + ks * 16 + half * 8;
        float4 a = *(const float4*)src;
        float4 c = *(const float4*)(src + 4);
        bf16x8 pk;
        pk[0] = (bf16)(a.x * SCALE_LOG2E); pk[1] = (bf16)(a.y * SCALE_LOG2E);
        pk[2] = (bf16)(a.z * SCALE_LOG2E); pk[3] = (bf16)(a.w * SCALE_LOG2E);
        pk[4] = (bf16)(c.x * SCALE_LOG2E); pk[5] = (bf16)(c.y * SCALE_LOG2E);
        pk[6] = (bf16)(c.z * SCALE_LOG2E); pk[7] = (bf16)(c.w * SCALE_LOG2E);
        qf[ks] = pk;
    }

    // ones A-frag: 32x16 matrix of 1.0 (denominator row-sum operand)
    bf16x8 ones;
    #pragma unroll
    for (int j = 0; j < 8; ++j) ones[j] = (bf16)1.0f;

    f32x16 acc[2] = {{}, {}};           // O^T tiles [mt_d] (unnormalized)
    f32x16 accL = {};                   // denominator (all rows identical)

    auto issue_dma = [&](int t, int sl) {
        const bf16* g = tiles + (size_t)t * 8192;
        #pragma unroll
        for (int j = 0; j < 4; ++j) {
            const int c = wv * 4 + j;             // 1 KB chunk 0..15
            __builtin_amdgcn_global_load_lds(GBL(g + c * 512 + lane * 8),
                                             LDS(&KV3[sl][c * 512]), 16, 0, 0);
        }
    };

    // S^T(tile it) = K Q^T into s: K frags JIT from ring slot it%3.
    // Two interleaved s-chains (R9 lesson: one chain = -5us).
    auto computeS = [&](int it, f32x16 (&s)[2]) {
        const bf16* bp = &KV3[it % 3][0];
        s[0] = f32x16{}; s[1] = f32x16{};
        #pragma unroll
        for (int ks = 0; ks < 4; ++ks) {
            bf16x8 k0 = *(const bf16x8*)&bp[((0 * 4 + ks) * 64 + lane) * 8];
            bf16x8 k1 = *(const bf16x8*)&bp[((1 * 4 + ks) * 64 + lane) * 8];
            s[0] = __builtin_amdgcn_mfma_f32_32x32x16_bf16(k0, qf[ks], s[0], 0, 0, 0);
            s[1] = __builtin_amdgcn_mfma_f32_32x32x16_bf16(k1, qf[ks], s[1], 0, 0, 0);
        }
    };
    // softmax + PV for tile it (V frags JIT from ring slot it%3).
    // Denominator via ones-MFMA (no VALU adds, no lacc).
    auto softpv = [&](int it, const f32x16 (&s)[2]) {
        const bf16* vp = &KV3[it % 3][4096];
        #pragma unroll
        for (int mt = 0; mt < 2; ++mt) {
            #pragma unroll
            for (int sp = 0; sp < 2; ++sp) {
                const int g = mt * 2 + sp;        // kv k-step 0..3
                bf16x8 v0 = *(const bf16x8*)&vp[((0 * 4 + g) * 64 + lane) * 8];
                bf16x8 v1 = *(const bf16x8*)&vp[((1 * 4 + g) * 64 + lane) * 8];
                float pv8[8];
                #pragma unroll
                for (int r = 0; r < 8; ++r) pv8[r] = __builtin_amdgcn_exp2f(s[mt][8 * sp + r]);
                bf16x4 lo = pack4(pv8[0], pv8[1], pv8[2], pv8[3]);
                bf16x4 hi = pack4(pv8[4], pv8[5], pv8[6], pv8[7]);
                bf16x8 bfrag = cswap(lo, hi);
                accL   = __builtin_amdgcn_mfma_f32_32x32x16_bf16(ones, bfrag, accL, 0, 0, 0);
                acc[0] = __builtin_amdgcn_mfma_f32_32x32x16_bf16(v0, bfrag, acc[0], 0, 0, 0);
                acc[1] = __builtin_amdgcn_mfma_f32_32x32x16_bf16(v1, bfrag, acc[1], 0, 0, 0);
            }
        }
    };

    f32x16 sA[2], sB[2];

    // prologue: fill slot 0, start slot 1, compute S(0)
    issue_dma(0, 0);
    __syncthreads();                              // DMA(0) complete
    issue_dma(1, 1);
    computeS(0, sA);

    // pipelined main loop: pairs (it, it+1) for it = 1,3,...,29
    #pragma unroll 1
    for (int it = 1; it < 31; it += 2) {
        __syncthreads();                          // DMA(it) complete; prev reads done
        issue_dma(it + 1, (it + 1) % 3);          // overwrites tile it-2 (consumed)
        computeS(it, sB);                         // MFMA pipe: S(it)
        softpv(it - 1, sA);                       // VALU/trans+MFMA: tile it-1
        __syncthreads();                          // DMA(it+1) complete
        issue_dma(it + 2, (it + 2) % 3);          // it+2 <= 31
        computeS(it + 1, sA);
        softpv(it, sB);
    }
    // tail: S(31) + softmax(30), then softmax(31)
    __syncthreads();                              // DMA(31) complete
    computeS(31, sB);
    softpv(30, sA);
    softpv(31, sB);

    // epilogue: denominator = accL row (MFMA summed all 32 kv rows per tile
    // across all tiles; every row identical, both halves hold the full sum)
    float inv = 1.0f / accL[0];
    const int qrow = q0 + l31;
    float* dst = out + ((size_t)bh * N_ + qrow) * D_ + 4 * half;
    #pragma unroll
    for (int mt = 0; mt < 2; ++mt)
        #pragma unroll
        for (int rq = 0; rq < 4; ++rq) {
            float4 o;
            o.x = acc[mt][4 * rq + 0] * inv;
            o.y = acc[mt][4 * rq + 1] * inv;
            o.z = acc[mt][4 * rq + 2] * inv;
            o.w = acc[mt][4 * rq + 3] * inv;
            *(float4*)(dst + mt * 32 + 8 * rq) = o;   // d = mt*32 + 8*rq + 4*half
        }
}

extern "C" void kernel_launch(void* const* d_in, const int* in_sizes, int n_in,
                              void* d_out, int out_size, void* d_ws, size_t ws_size,
                              hipStream_t stream) {
    const float* q = (const float*)d_in[0];
    const float* k = (const float*)d_in[1];
    const float* v = (const float*)d_in[2];
    float* out = (float*)d_out;

    bf16* img = (bf16*)d_ws;                      // 128 tiles x 16 KB = 2 MB

    convert_kv<<<B_ * 32, 512, 0, stream>>>(k, v, img);
    dim3 grid(N_ / BM, B_ * H_);
    attn_fwd<<<grid, 256, 0, stream>>>(q, img, out);
}

// Round 12
// 157.081 us; speedup vs baseline: 1.0057x; 1.0057x over previous
//
#include <hip/hip_runtime.h>
#include <hip/hip_bf16.h>

#define B_ 4
#define H_ 16
#define N_ 2048
#define D_ 64
#define BM 256   // q-rows per WG (64 per wave, 4 waves)

typedef __bf16 bf16;
typedef bf16 bf16x4 __attribute__((ext_vector_type(4)));
typedef bf16 bf16x8 __attribute__((ext_vector_type(8)));
typedef float f32x16 __attribute__((ext_vector_type(16)));
typedef unsigned u32x2 __attribute__((ext_vector_type(2)));
typedef unsigned u32x4 __attribute__((ext_vector_type(4)));

#define SCALE_LOG2E 0.18033688011112042f  // (1/sqrt(64)) * log2(e)

#define GBL(p) ((const __attribute__((address_space(1))) void*)(p))
#define LDS(p) ((__attribute__((address_space(3))) void*)(p))

// Per (b, kv-tile T of 64): 16 KB image in per-lane FRAGMENT ORDER for 32x32x16 MFMA.
//   K half  [0,8KB):  unit p=(mt*4+ks)*64+ln : A-frag K[kv=T*64+mt*32+(ln&31)][d=ks*16+(ln>>5)*8 ..+8]
//   V half  [8,16KB): unit p=(mt*4+ks)*64+ln : A-frag V^T[d=mt*32+(ln&31)][kv=T*64+ks*16+(ln>>5)*8 ..+8]
// V transpose via LDS: coalesced float4 row reads -> padded LDS -> fragment-order
// reads -> coalesced bf16x8 store. One block per tile.
__global__ __launch_bounds__(512) void convert_kv(const float* __restrict__ k,
                                                  const float* __restrict__ v,
                                                  bf16* __restrict__ img) {
    __shared__ bf16 VT[64][66];                   // stride 66 elems (132 B)
    const int tile = blockIdx.x;                  // b*32 + T
    const int b = tile >> 5, T = tile & 31;
    const int t = threadIdx.x;                    // 0..511 == unit id
    bf16* timg = img + (size_t)tile * 8192;       // 16 KB per tile

    const int mtks = t >> 6;
    const int ln   = t & 63;
    const int mt = mtks >> 2, ks = mtks & 3;

    // --- K half: direct, coalesced both sides ---
    {
        const int kvr = T * 64 + mt * 32 + (ln & 31);
        const int d0  = ks * 16 + (ln >> 5) * 8;
        const float* src = k + ((size_t)b * N_ + kvr) * D_ + d0;
        float4 a = *(const float4*)src;
        float4 c = *(const float4*)(src + 4);
        bf16x8 o;
        o[0] = (bf16)a.x; o[1] = (bf16)a.y; o[2] = (bf16)a.z; o[3] = (bf16)a.w;
        o[4] = (bf16)c.x; o[5] = (bf16)c.y; o[6] = (bf16)c.z; o[7] = (bf16)c.w;
        *(bf16x8*)(timg + t * 8) = o;
    }

    // --- V half phase 1: coalesced row load -> LDS bf16 ---
    {
        const int kv = t >> 3;                    // 0..63 (tile-local row)
        const int c8 = (t & 7) * 8;               // 0..56
        const float* src = v + ((size_t)b * N_ + T * 64 + kv) * D_ + c8;
        float4 a = *(const float4*)src;
        float4 c = *(const float4*)(src + 4);
        VT[kv][c8 + 0] = (bf16)a.x; VT[kv][c8 + 1] = (bf16)a.y;
        VT[kv][c8 + 2] = (bf16)a.z; VT[kv][c8 + 3] = (bf16)a.w;
        VT[kv][c8 + 4] = (bf16)c.x; VT[kv][c8 + 5] = (bf16)c.y;
        VT[kv][c8 + 6] = (bf16)c.z; VT[kv][c8 + 7] = (bf16)c.w;
    }
    __syncthreads();
    // --- V half phase 2: fragment-order read, coalesced store ---
    {
        const int d   = mt * 32 + (ln & 31);
        const int kv0 = ks * 16 + (ln >> 5) * 8;  // tile-local
        bf16x8 o;
        #pragma unroll
        for (int j = 0; j < 8; ++j) o[j] = VT[kv0 + j][d];
        *(bf16x8*)(timg + 4096 + t * 8) = o;
    }
}

static __device__ inline bf16x4 pack4(float a, float b, float c, float d) {
    bf16x4 r; r[0] = (bf16)a; r[1] = (bf16)b; r[2] = (bf16)c; r[3] = (bf16)d; return r;
}

// C->B half-wave exchange via v_permlane32_swap_b32. For (p,q) = swap(L,H):
//   p = {L.row0, H.row0}  == (half ? xhi : lo)
//   q = {L.row1, H.row1}  == (half ? hi  : xlo)
static __device__ inline bf16x8 cswap(bf16x4 lo, bf16x4 hi) {
    u32x2 l = __builtin_bit_cast(u32x2, lo);
    u32x2 h = __builtin_bit_cast(u32x2, hi);
    u32x2 r0 = __builtin_amdgcn_permlane32_swap(l[0], h[0], false, false);
    u32x2 r1 = __builtin_amdgcn_permlane32_swap(l[1], h[1], false, false);
    u32x4 o; o[0] = r0[0]; o[1] = r1[0]; o[2] = r0[1]; o[3] = r1[1];
    return __builtin_bit_cast(bf16x8, o);
}

// Flash attention, 32x32x16 MFMA, S^T/O^T orientation, P in registers.
//
// Round-12 = R8's one-tile software pipeline at DOUBLE BODY SIZE (BM=256,
// 64 q-rows/wave as two qn-subtiles). Rationale: R8's waves issue ~1160cy
// per ~6000cy body (80% idle on fixed per-body costs: barrier skew, DMA
// drain, chain tails) and 2 waves/SIMD is a hard floor (m69: occupancy
// quantizes at 128/256 regs -- no 3-wave config exists; R9 confirmed).
// Doubling the body amortizes the fixed costs 2x, halves barriers and KV
// DMA/L2 traffic per unit work, at ZERO extra occupancy cost (stays in
// the 256-reg band: qf 32 + acc 64 + sQ 64 + arch ~70 ~= 230 < 256).
// Schedule keeps R8's interleave per qn: softpv(t,qn) then S(t+1,qn) --
// each PV chain's latency tail is covered by the next independent S block
// (R9 two-chain rule preserved; R10/R11 lessons: no extra regs, no extra
// MFMAs).
__global__ __launch_bounds__(256, 2) void attn_fwd(const float* __restrict__ q,
                                                   const bf16* __restrict__ img,
                                                   float* __restrict__ out) {
    __shared__ __align__(16) bf16 KV3[3][8192];   // 3-slot ring, 48 KB

    const int tid  = threadIdx.x;
    const int lane = tid & 63;
    const int wv   = tid >> 6;          // 0..3
    const int half = lane >> 5;
    const int l31  = lane & 31;

    const int bh = blockIdx.y;
    const int b  = bh >> 4;
    const int q0 = blockIdx.x * BM + wv * 64;

    const bf16* tiles = img + (size_t)b * 32 * 8192;

    // Q frags (B-layout for S^T: n=q=l31, k=d=ks*16+half*8+j), pre-scaled
    bf16x8 qf[2][4];
    #pragma unroll
    for (int qn = 0; qn < 2; ++qn)
        #pragma unroll
        for (int ks = 0; ks < 4; ++ks) {
            const float* src = q + ((size_t)bh * N_ + q0 + qn * 32 + l31) * D_ + ks * 16 + half * 8;
            float4 a = *(const float4*)src;
            float4 c = *(const float4*)(src + 4);
            bf16x8 pk;
            pk[0] = (bf16)(a.x * SCALE_LOG2E); pk[1] = (bf16)(a.y * SCALE_LOG2E);
            pk[2] = (bf16)(a.z * SCALE_LOG2E); pk[3] = (bf16)(a.w * SCALE_LOG2E);
            pk[4] = (bf16)(c.x * SCALE_LOG2E); pk[5] = (bf16)(c.y * SCALE_LOG2E);
            pk[6] = (bf16)(c.z * SCALE_LOG2E); pk[7] = (bf16)(c.w * SCALE_LOG2E);
            qf[qn][ks] = pk;
        }

    f32x16 acc[2][2] = {{{}, {}}, {{}, {}}};      // O^T [mt][qn] (unnormalized)
    float lacc[2] = {0.f, 0.f};

    auto issue_dma = [&](int t, int sl) {
        const bf16* g = tiles + (size_t)t * 8192;
        #pragma unroll
        for (int j = 0; j < 4; ++j) {
            const int c = wv * 4 + j;             // 1 KB chunk 0..15
            __builtin_amdgcn_global_load_lds(GBL(g + c * 512 + lane * 8),
                                             LDS(&KV3[sl][c * 512]), 16, 0, 0);
        }
    };

    // S^T(tile it, qn) = K Q^T: K frags JIT from ring slot it%3.
    // Two interleaved mt-chains (R9 lesson: one chain = -5us).
    auto computeS = [&](int it, int qn, f32x16 (&s)[2]) {
        const bf16* bp = &KV3[it % 3][0];
        s[0] = f32x16{}; s[1] = f32x16{};
        #pragma unroll
        for (int ks = 0; ks < 4; ++ks) {
            bf16x8 k0 = *(const bf16x8*)&bp[((0 * 4 + ks) * 64 + lane) * 8];
            bf16x8 k1 = *(const bf16x8*)&bp[((1 * 4 + ks) * 64 + lane) * 8];
            s[0] = __builtin_amdgcn_mfma_f32_32x32x16_bf16(k0, qf[qn][ks], s[0], 0, 0, 0);
            s[1] = __builtin_amdgcn_mfma_f32_32x32x16_bf16(k1, qf[qn][ks], s[1], 0, 0, 0);
        }
    };
    // softmax + PV for (tile it, qn); V frags JIT from ring slot it%3.
    // Denominator on VALU (R11 lesson: ones-MFMA contends the pipelined MFMA pipe).
    auto softpv = [&](int it, int qn, const f32x16 (&s)[2]) {
        const bf16* vp = &KV3[it % 3][4096];
        #pragma unroll
        for (int mt = 0; mt < 2; ++mt) {
            #pragma unroll
            for (int sp = 0; sp < 2; ++sp) {
                const int g = mt * 2 + sp;        // kv k-step 0..3
                bf16x8 v0 = *(const bf16x8*)&vp[((0 * 4 + g) * 64 + lane) * 8];
                bf16x8 v1 = *(const bf16x8*)&vp[((1 * 4 + g) * 64 + lane) * 8];
                float pv8[8];
                #pragma unroll
                for (int r = 0; r < 8; ++r) pv8[r] = __builtin_amdgcn_exp2f(s[mt][8 * sp + r]);
                lacc[qn] += ((pv8[0] + pv8[1]) + (pv8[2] + pv8[3]))
                          + ((pv8[4] + pv8[5]) + (pv8[6] + pv8[7]));
                bf16x4 lo = pack4(pv8[0], pv8[1], pv8[2], pv8[3]);
                bf16x4 hi = pack4(pv8[4], pv8[5], pv8[6], pv8[7]);
                bf16x8 bfrag = cswap(lo, hi);
                acc[0][qn] = __builtin_amdgcn_mfma_f32_32x32x16_bf16(v0, bfrag, acc[0][qn], 0, 0, 0);
                acc[1][qn] = __builtin_amdgcn_mfma_f32_32x32x16_bf16(v1, bfrag, acc[1][qn], 0, 0, 0);
            }
        }
    };

    f32x16 sQ0[2], sQ1[2];              // S state per qn (named; rule #20)

    // prologue: fill slot 0, start slot 1, compute S(0) for both qn
    issue_dma(0, 0);
    __syncthreads();                              // DMA(0) complete
    issue_dma(1, 1);
    computeS(0, 0, sQ0);
    computeS(0, 1, sQ1);

    // steady state: per tile t, softpv(t,qn) then S(t+1,qn) per qn.
    // Barrier at loop top: DMA(t+1) complete; slot t-1 reads (prev iter) done.
    #pragma unroll 1
    for (int t = 0; t < 31; ++t) {
        __syncthreads();
        if (t + 2 < 32) issue_dma(t + 2, (t + 2) % 3);
        softpv(t, 0, sQ0);                        // exp2 on old S; PV chain...
        computeS(t + 1, 0, sQ0);                  // ...covered by independent S block
        softpv(t, 1, sQ1);
        computeS(t + 1, 1, sQ1);
    }
    // tail: tile 31 (S computed in t=30 body; DMA(31) drained at t=30 barrier)
    softpv(31, 0, sQ0);
    softpv(31, 1, sQ1);

    // epilogue: denominator = own + partner half-wave partial; store float4
    #pragma unroll
    for (int qn = 0; qn < 2; ++qn) {
        float l = lacc[qn] + __shfl_xor(lacc[qn], 32);
        float inv = 1.0f / l;
        const int qrow = q0 + qn * 32 + l31;
        float* dst = out + ((size_t)bh * N_ + qrow) * D_ + 4 * half;
        #pragma unroll
        for (int mt = 0; mt < 2; ++mt)
            #pragma unroll
            for (int rq = 0; rq < 4; ++rq) {
                float4 o;
                o.x = acc[mt][qn][4 * rq + 0] * inv;
                o.y = acc[mt][qn][4 * rq + 1] * inv;
                o.z = acc[mt][qn][4 * rq + 2] * inv;
                o.w = acc[mt][qn][4 * rq + 3] * inv;
                *(float4*)(dst + mt * 32 + 8 * rq) = o;   // d = mt*32 + 8*rq + 4*half
            }
    }
}

extern "C" void kernel_launch(void* const* d_in, const int* in_sizes, int n_in,
                              void* d_out, int out_size, void* d_ws, size_t ws_size,
                              hipStream_t stream) {
    const float* q = (const float*)d_in[0];
    const float* k = (const float*)d_in[1];
    const float* v = (const float*)d_in[2];
    float* out = (float*)d_out;

    bf16* img = (bf16*)d_ws;                      // 128 tiles x 16 KB = 2 MB

    convert_kv<<<B_ * 32, 512, 0, stream>>>(k, v, img);
    dim3 grid(N_ / BM, B_ * H_);
    attn_fwd<<<grid, 256, 0, stream>>>(q, img, out);
}

// Round 13
// 152.481 us; speedup vs baseline: 1.0360x; 1.0302x over previous
//
#include <hip/hip_runtime.h>
#include <hip/hip_bf16.h>

#define B_ 4
#define H_ 16
#define N_ 2048
#define D_ 64
#define BM 128   // q-rows per WG (32 per wave, 4 waves)

typedef __bf16 bf16;
typedef bf16 bf16x4 __attribute__((ext_vector_type(4)));
typedef bf16 bf16x8 __attribute__((ext_vector_type(8)));
typedef float f32x16 __attribute__((ext_vector_type(16)));
typedef unsigned u32x2 __attribute__((ext_vector_type(2)));
typedef unsigned u32x4 __attribute__((ext_vector_type(4)));

#define SCALE_LOG2E 0.18033688011112042f  // (1/sqrt(64)) * log2(e)

#define GBL(p) ((const __attribute__((address_space(1))) void*)(p))
#define LDS(p) ((__attribute__((address_space(3))) void*)(p))

// Per (b, kv-tile T of 64): 16 KB image in per-lane FRAGMENT ORDER for 32x32x16 MFMA.
//   K half  [0,8KB):  unit p=(mt*4+ks)*64+ln : A-frag K[kv=T*64+mt*32+(ln&31)][d=ks*16+(ln>>5)*8 ..+8]
//   V half  [8,16KB): unit p=(mt*4+ks)*64+ln : A-frag V^T[d=mt*32+(ln&31)][kv=T*64+ks*16+(ln>>5)*8 ..+8]
// V transpose via LDS: coalesced float4 row reads -> padded LDS -> fragment-order
// reads -> coalesced bf16x8 store. One block per tile.
__global__ __launch_bounds__(512) void convert_kv(const float* __restrict__ k,
                                                  const float* __restrict__ v,
                                                  bf16* __restrict__ img) {
    __shared__ bf16 VT[64][66];                   // stride 66 elems (132 B)
    const int tile = blockIdx.x;                  // b*32 + T
    const int b = tile >> 5, T = tile & 31;
    const int t = threadIdx.x;                    // 0..511 == unit id
    bf16* timg = img + (size_t)tile * 8192;       // 16 KB per tile

    const int mtks = t >> 6;
    const int ln   = t & 63;
    const int mt = mtks >> 2, ks = mtks & 3;

    // --- K half: direct, coalesced both sides ---
    {
        const int kvr = T * 64 + mt * 32 + (ln & 31);
        const int d0  = ks * 16 + (ln >> 5) * 8;
        const float* src = k + ((size_t)b * N_ + kvr) * D_ + d0;
        float4 a = *(const float4*)src;
        float4 c = *(const float4*)(src + 4);
        bf16x8 o;
        o[0] = (bf16)a.x; o[1] = (bf16)a.y; o[2] = (bf16)a.z; o[3] = (bf16)a.w;
        o[4] = (bf16)c.x; o[5] = (bf16)c.y; o[6] = (bf16)c.z; o[7] = (bf16)c.w;
        *(bf16x8*)(timg + t * 8) = o;
    }

    // --- V half phase 1: coalesced row load -> LDS bf16 ---
    {
        const int kv = t >> 3;                    // 0..63 (tile-local row)
        const int c8 = (t & 7) * 8;               // 0..56
        const float* src = v + ((size_t)b * N_ + T * 64 + kv) * D_ + c8;
        float4 a = *(const float4*)src;
        float4 c = *(const float4*)(src + 4);
        VT[kv][c8 + 0] = (bf16)a.x; VT[kv][c8 + 1] = (bf16)a.y;
        VT[kv][c8 + 2] = (bf16)a.z; VT[kv][c8 + 3] = (bf16)a.w;
        VT[kv][c8 + 4] = (bf16)c.x; VT[kv][c8 + 5] = (bf16)c.y;
        VT[kv][c8 + 6] = (bf16)c.z; VT[kv][c8 + 7] = (bf16)c.w;
    }
    __syncthreads();
    // --- V half phase 2: fragment-order read, coalesced store ---
    {
        const int d   = mt * 32 + (ln & 31);
        const int kv0 = ks * 16 + (ln >> 5) * 8;  // tile-local
        bf16x8 o;
        #pragma unroll
        for (int j = 0; j < 8; ++j) o[j] = VT[kv0 + j][d];
        *(bf16x8*)(timg + 4096 + t * 8) = o;
    }
}

static __device__ inline bf16x4 pack4(float a, float b, float c, float d) {
    bf16x4 r; r[0] = (bf16)a; r[1] = (bf16)b; r[2] = (bf16)c; r[3] = (bf16)d; return r;
}

// C->B half-wave exchange via v_permlane32_swap_b32. For (p,q) = swap(L,H):
//   p = {L.row0, H.row0}  == (half ? xhi : lo)
//   q = {L.row1, H.row1}  == (half ? hi  : xlo)
static __device__ inline bf16x8 cswap(bf16x4 lo, bf16x4 hi) {
    u32x2 l = __builtin_bit_cast(u32x2, lo);
    u32x2 h = __builtin_bit_cast(u32x2, hi);
    u32x2 r0 = __builtin_amdgcn_permlane32_swap(l[0], h[0], false, false);
    u32x2 r1 = __builtin_amdgcn_permlane32_swap(l[1], h[1], false, false);
    u32x4 o; o[0] = r0[0]; o[1] = r1[0]; o[2] = r0[1]; o[3] = r1[1];
    return __builtin_bit_cast(bf16x8, o);
}

// Flash attention, 32x32x16 MFMA, S^T/O^T orientation, P in registers.
//
// FINAL (= R8, session champion: 80.2us attn, 151.8us total).
// One-tile software pipeline: iteration body = { S-MFMAs(tile t) ||
// softmax+PV(tile t-1) } so the exp2 block never depends on just-issued
// MFMAs; S results are consumed a full iteration (~500cy) later. 3-slot
// LDS ring (mod-3: DMA write slot provably != both read slots).
//
// Session evidence (13 measured variants): this is a sharp local optimum.
//  - pipeline (this): -10% vs the ~90us plateau. The ONLY win.
//  - occupancy 8->16 w/CU (R3): null. Free-running, no barriers (R5): null.
//  - reg prefetch depth (R6): -7%. setprio (R4): -3%.
//  - ones-MFMA denominator: free when barrier-locked (R7), -8% here (R11:
//    contends the pipelined MFMA pipe).
//  - fewer S chains (R9): -6% (MFMA result latency needs 2 chains).
//  - PV chain split +32 regs (R10): -5% (occupancy). Body x2 (R12): -7%
//    (spill: FETCH 24.6->29.8MB, WRITE 32.8->51.9MB).
// Every perturbation loses on the register/occupancy/MFMA-contention
// triangle; per-wave state exactly fills the 2-wave/SIMD band.
__global__ __launch_bounds__(256, 2) void attn_fwd(const float* __restrict__ q,
                                                   const bf16* __restrict__ img,
                                                   float* __restrict__ out) {
    __shared__ __align__(16) bf16 KV3[3][8192];   // 3-slot ring, 48 KB

    const int tid  = threadIdx.x;
    const int lane = tid & 63;
    const int wv   = tid >> 6;          // 0..3
    const int half = lane >> 5;
    const int l31  = lane & 31;

    const int bh = blockIdx.y;
    const int b  = bh >> 4;
    const int q0 = blockIdx.x * BM + wv * 32;

    const bf16* tiles = img + (size_t)b * 32 * 8192;

    // Q frags (B-layout for S^T: n=q=l31, k=d=ks*16+half*8+j), pre-scaled
    bf16x8 qf[4];
    #pragma unroll
    for (int ks = 0; ks < 4; ++ks) {
        const float* src = q + ((size_t)bh * N_ + q0 + l31) * D_ + ks * 16 + half * 8;
        float4 a = *(const float4*)src;
        float4 c = *(const float4*)(src + 4);
        bf16x8 pk;
        pk[0] = (bf16)(a.x * SCALE_LOG2E); pk[1] = (bf16)(a.y * SCALE_LOG2E);
        pk[2] = (bf16)(a.z * SCALE_LOG2E); pk[3] = (bf16)(a.w * SCALE_LOG2E);
        pk[4] = (bf16)(c.x * SCALE_LOG2E); pk[5] = (bf16)(c.y * SCALE_LOG2E);
        pk[6] = (bf16)(c.z * SCALE_LOG2E); pk[7] = (bf16)(c.w * SCALE_LOG2E);
        qf[ks] = pk;
    }

    f32x16 acc[2] = {{}, {}};           // O^T tiles [mt_d] (unnormalized)
    float lacc = 0.f;

    auto issue_dma = [&](int t, int sl) {
        const bf16* g = tiles + (size_t)t * 8192;
        #pragma unroll
        for (int j = 0; j < 4; ++j) {
            const int c = wv * 4 + j;             // 1 KB chunk 0..15
            __builtin_amdgcn_global_load_lds(GBL(g + c * 512 + lane * 8),
                                             LDS(&KV3[sl][c * 512]), 16, 0, 0);
        }
    };

    // S^T(tile it) = K Q^T into s: K frags JIT from ring slot it%3.
    // Two interleaved s-chains (R9: one chain = -5us).
    auto computeS = [&](int it, f32x16 (&s)[2]) {
        const bf16* bp = &KV3[it % 3][0];
        s[0] = f32x16{}; s[1] = f32x16{};
        #pragma unroll
        for (int ks = 0; ks < 4; ++ks) {
            bf16x8 k0 = *(const bf16x8*)&bp[((0 * 4 + ks) * 64 + lane) * 8];
            bf16x8 k1 = *(const bf16x8*)&bp[((1 * 4 + ks) * 64 + lane) * 8];
            s[0] = __builtin_amdgcn_mfma_f32_32x32x16_bf16(k0, qf[ks], s[0], 0, 0, 0);
            s[1] = __builtin_amdgcn_mfma_f32_32x32x16_bf16(k1, qf[ks], s[1], 0, 0, 0);
        }
    };
    // softmax + PV for tile it (V frags JIT from ring slot it%3).
    // Denominator on VALU (R11: ones-MFMA contends the pipelined MFMA pipe).
    auto softpv = [&](int it, const f32x16 (&s)[2]) {
        const bf16* vp = &KV3[it % 3][4096];
        #pragma unroll
        for (int mt = 0; mt < 2; ++mt) {
            #pragma unroll
            for (int sp = 0; sp < 2; ++sp) {
                const int g = mt * 2 + sp;        // kv k-step 0..3
                bf16x8 v0 = *(const bf16x8*)&vp[((0 * 4 + g) * 64 + lane) * 8];
                bf16x8 v1 = *(const bf16x8*)&vp[((1 * 4 + g) * 64 + lane) * 8];
                float pv8[8];
                #pragma unroll
                for (int r = 0; r < 8; ++r) pv8[r] = __builtin_amdgcn_exp2f(s[mt][8 * sp + r]);
                lacc += ((pv8[0] + pv8[1]) + (pv8[2] + pv8[3]))
                      + ((pv8[4] + pv8[5]) + (pv8[6] + pv8[7]));
                bf16x4 lo = pack4(pv8[0], pv8[1], pv8[2], pv8[3]);
                bf16x4 hi = pack4(pv8[4], pv8[5], pv8[6], pv8[7]);
                bf16x8 bfrag = cswap(lo, hi);
                acc[0] = __builtin_amdgcn_mfma_f32_32x32x16_bf16(v0, bfrag, acc[0], 0, 0, 0);
                acc[1] = __builtin_amdgcn_mfma_f32_32x32x16_bf16(v1, bfrag, acc[1], 0, 0, 0);
            }
        }
    };

    f32x16 sA[2], sB[2];

    // prologue: fill slot 0, start slot 1, compute S(0)
    issue_dma(0, 0);
    __syncthreads();                              // DMA(0) complete
    issue_dma(1, 1);
    computeS(0, sA);

    // pipelined main loop: pairs (it, it+1) for it = 1,3,...,29
    #pragma unroll 1
    for (int it = 1; it < 31; it += 2) {
        __syncthreads();                          // DMA(it) complete; prev reads done
        issue_dma(it + 1, (it + 1) % 3);          // overwrites tile it-2 (consumed)
        computeS(it, sB);                         // MFMA pipe: S(it)
        softpv(it - 1, sA);                       // VALU/trans+MFMA: tile it-1
        __syncthreads();                          // DMA(it+1) complete
        issue_dma(it + 2, (it + 2) % 3);          // it+2 <= 31
        computeS(it + 1, sA);
        softpv(it, sB);
    }
    // tail: S(31) + softmax(30), then softmax(31)
    __syncthreads();                              // DMA(31) complete
    computeS(31, sB);
    softpv(30, sA);
    softpv(31, sB);

    // epilogue: denominator = own + partner half-wave partial; store float4
    float l = lacc + __shfl_xor(lacc, 32);
    float inv = 1.0f / l;
    const int qrow = q0 + l31;
    float* dst = out + ((size_t)bh * N_ + qrow) * D_ + 4 * half;
    #pragma unroll
    for (int mt = 0; mt < 2; ++mt)
        #pragma unroll
        for (int rq = 0; rq < 4; ++rq) {
            float4 o;
            o.x = acc[mt][4 * rq + 0] * inv;
            o.y = acc[mt][4 * rq + 1] * inv;
            o.z = acc[mt][4 * rq + 2] * inv;
            o.w = acc[mt][4 * rq + 3] * inv;
            *(float4*)(dst + mt * 32 + 8 * rq) = o;   // d = mt*32 + 8*rq + 4*half
        }
}

extern "C" void kernel_launch(void* const* d_in, const int* in_sizes, int n_in,
                              void* d_out, int out_size, void* d_ws, size_t ws_size,
                              hipStream_t stream) {
    const float* q = (const float*)d_in[0];
    const float* k = (const float*)d_in[1];
    const float* v = (const float*)d_in[2];
    float* out = (float*)d_out;

    bf16* img = (bf16*)d_ws;                      // 128 tiles x 16 KB = 2 MB

    convert_kv<<<B_ * 32, 512, 0, stream>>>(k, v, img);
    dim3 grid(N_ / BM, B_ * H_);
    attn_fwd<<<grid, 256, 0, stream>>>(q, img, out);
}